// Round 5
// baseline (105.521 us; speedup 1.0000x reference)
//
#include <hip/hip_runtime.h>
#include <hip/hip_bf16.h>

// SCAN similarity: out[i,c] = t2i[c,i] + i2t[c,i]
// g (global sim) cancels in the renormalization -> img_mean/cap_mean unused.
// bf16 MFMA, packed-A (no pad rows): block = 4 imgs (144 rows) x 4 caps (192 cols),
// 4 waves, wave = 9 row-tiles x 1 cap (27 MFMA : 12 ds_read_b128 per K32 chunk).
// global_load_lds dbuf + XOR swizzle; 4-round in-LDS softmax epilogue.

#define EPSF 1e-8f
#define LAMF 9.0f

constexpr int IN = 128, CN = 128, RN = 36, WN = 48, DN = 1024;
constexpr size_t NIMG = (size_t)IN * RN * DN;   // 4718592 elems

constexpr int AROWS = 4 * RN;          // 144
constexpr int BROWS = 4 * WN;          // 192
constexpr int TROWS = AROWS + BROWS;   // 336 rows x 64 B = 21504 B per buffer
constexpr int BUFB  = TROWS * 64;      // 21504
constexpr int NGRAN = TROWS * 4;       // 1344 16B-granules per buffer

using short8 = __attribute__((ext_vector_type(8))) short;
using f32x4  = __attribute__((ext_vector_type(4))) float;

__device__ __forceinline__ float leaky(float x) { return x > 0.f ? x : 0.1f * x; }

__device__ __forceinline__ unsigned short f2bf(float f) {
    unsigned int b = __float_as_uint(f);
    b += 0x7FFFu + ((b >> 16) & 1u);          // round-to-nearest-even
    return (unsigned short)(b >> 16);
}

__device__ __forceinline__ void gld_lds16(const unsigned short* g, void* l) {
    __builtin_amdgcn_global_load_lds(
        (const __attribute__((address_space(1))) unsigned int*)g,
        (__attribute__((address_space(3))) unsigned int*)l,
        16, 0, 0);
}

// ---------- preprocess: f32 -> bf16 ----------
__global__ void cvt_bf16(const float* __restrict__ in, unsigned short* __restrict__ out, int n4) {
    int idx = blockIdx.x * blockDim.x + threadIdx.x;
    if (idx >= n4) return;
    float4 v = ((const float4*)in)[idx];
    ushort4 o;
    o.x = f2bf(v.x); o.y = f2bf(v.y); o.z = f2bf(v.z); o.w = f2bf(v.w);
    ((ushort4*)out)[idx] = o;
}

// ---------- main MFMA kernel ----------
__global__ __launch_bounds__(256, 3) void scan_mfma(
    const unsigned short* __restrict__ wsb,   // imgh @0 [128][36][1024], caph @NIMG [128][48][1024]
    float* __restrict__ out)                  // [128][128], out[i*128+c]
{
    // staging dbuf: 2 x 21504 B. epilogue aliases (behind GEMM's final barrier):
    //   sS[4][36][49] @0 (28224) | sncol @28224 (768) | snrow @28992 (576)
    //   scw @29568 (768) | scr @30336 (576) -> 30912
    __shared__ __align__(16) unsigned char smem[2 * BUFB];
    float (*sS)[RN][WN + 1] = (float (*)[RN][WN + 1])smem;
    float* sncol = (float*)(smem + 28224);   // [4][48] : LAMF / col_norm
    float* snrow = (float*)(smem + 28992);   // [4][36] : LAMF / row_norm
    float* scw   = (float*)(smem + 29568);   // [4][48]
    float* scr   = (float*)(smem + 30336);   // [4][36]

    const int t    = threadIdx.x;
    const int lane = t & 63;
    const int wid  = t >> 6;      // 0..3 ; wave's caption index
    const int lr   = lane & 15;
    const int lg   = lane >> 4;   // 0..3

    const int bi = blockIdx.x;    // image block (4 images)
    const int bc = blockIdx.y;    // caption block (4 captions)

    // ---- loop-invariant staging source offsets (elements) ----
    // granules g = j*256 + wid*64 + lane (j=0..4) and tail g = 1280 + t (t<64)
    unsigned int soff[6];
#pragma unroll
    for (int j = 0; j < 6; ++j) {
        int g = (j < 5) ? (j * 256 + t) : (1280 + t);
        int row = g >> 2, cg = g & 3;
        int sg = cg ^ ((row >> 1) & 3);
        unsigned int off;
        if (row < AROWS)
            off = (unsigned int)((bi * AROWS + row) << 10) + sg * 8;
        else
            off = (unsigned int)NIMG + (unsigned int)((bc * BROWS + (row - AROWS)) << 10) + sg * 8;
        soff[j] = off;
    }

    // fragment read swizzle (byte offset of this lane's 16B granule within its row)
    const int glo = ((lg ^ ((lr >> 1) & 3)) << 4);

    f32x4 acc[9][3];
#pragma unroll
    for (int rt = 0; rt < 9; ++rt)
#pragma unroll
        for (int ct = 0; ct < 3; ++ct) acc[rt][ct] = (f32x4)(0.f);

    auto stage = [&](int bsel, int d0) {
        char* bufp = (char*)smem + bsel * BUFB;
#pragma unroll
        for (int j = 0; j < 5; ++j)
            gld_lds16(wsb + soff[j] + d0, bufp + j * 4096 + wid * 1024);
        if (t < 64)
            gld_lds16(wsb + soff[5] + d0, bufp + 20480);
    };

    stage(0, 0);
    __syncthreads();

    for (int ch = 0; ch < 32; ++ch) {
        if (ch < 31) stage((ch & 1) ^ 1, (ch + 1) * 32);

        const char* bufp = (const char*)smem + (ch & 1) * BUFB;
        const char* ap = bufp + lr * 64 + glo;                                  // rt stride 1024
        const char* bp = bufp + (AROWS + wid * WN + lr) * 64 + glo;             // ct stride 1024
        short8 b0 = *(const short8*)(bp);
        short8 b1 = *(const short8*)(bp + 1024);
        short8 b2 = *(const short8*)(bp + 2048);

        __builtin_amdgcn_s_setprio(1);
#pragma unroll
        for (int rt = 0; rt < 9; ++rt) {
            short8 a = *(const short8*)(ap + rt * 1024);
            acc[rt][0] = __builtin_amdgcn_mfma_f32_16x16x32_bf16(a, b0, acc[rt][0], 0, 0, 0);
            acc[rt][1] = __builtin_amdgcn_mfma_f32_16x16x32_bf16(a, b1, acc[rt][1], 0, 0, 0);
            acc[rt][2] = __builtin_amdgcn_mfma_f32_16x16x32_bf16(a, b2, acc[rt][2], 0, 0, 0);
        }
        __builtin_amdgcn_s_setprio(0);
        __syncthreads();
    }

    // ---- epilogue: 4 rounds, round r = image bi*4+r, 4 tiles (one per cap/wave) ----
    // C/D layout: col = lane&15, row = (lane>>4)*4 + reg   [m89-verified]
#pragma unroll
    for (int r = 0; r < 4; ++r) {
        if (r > 0 && t < 4) {
            // finalize round r-1 (reads scr/scw; disjoint from sS writes below;
            // softmax for round r writes scr/scw only after two more barriers)
            float s1 = 0.f, s2 = 0.f;
            for (int w = 0; w < WN; ++w) s1 += scw[t * WN + w];
            for (int rr = 0; rr < RN; ++rr) s2 += scr[t * RN + rr];
            out[(size_t)(bi * 4 + (r - 1)) * CN + (bc * 4 + t)] = s1 / (float)WN + s2 / (float)RN;
        }
        // dump: each wave writes rows of image r from its acc (tile slot = wid)
#pragma unroll
        for (int rt = 0; rt < 9; ++rt)
#pragma unroll
            for (int reg = 0; reg < 4; ++reg) {
                int lrow = rt * 16 + lg * 4 + reg;     // 0..143
                int ii = lrow / 36;
                if (ii == r) {
                    int rin = lrow - ii * 36;
#pragma unroll
                    for (int ct = 0; ct < 3; ++ct)
                        sS[wid][rin][ct * 16 + lr] = acc[rt][ct][reg];
                }
            }
        __syncthreads();

        // inverse l2 norms (scaled by LAMF)
        if (t < 4 * WN) {                       // col norms over r
            int tile = t / WN, w = t % WN;
            float ss = 0.f;
            for (int rr = 0; rr < RN; ++rr) { float l = leaky(sS[tile][rr][w]); ss = fmaf(l, l, ss); }
            sncol[t] = LAMF / (sqrtf(ss + EPSF) + EPSF);
        }
        if (t < 4 * RN) {                       // row norms over w
            int tile = t / RN, rr = t % RN;
            float ss = 0.f;
            for (int w = 0; w < WN; ++w) { float l = leaky(sS[tile][rr][w]); ss = fmaf(l, l, ss); }
            snrow[t] = LAMF / (sqrtf(ss + EPSF) + EPSF);
        }
        __syncthreads();

        // single-pass softmaxes (arg bounded by LAMF => no max pass)
        if (t < 4 * RN) {                       // i2t: softmax over w per row
            int tile = t / RN, rr = t % RN;
            const float* Sr = sS[tile][rr];
            const float* ic = sncol + tile * WN;
            float se = 0.f, sw = 0.f;
            for (int w = 0; w < WN; ++w) {
                float s = Sr[w];
                float e = __expf(leaky(s) * ic[w]);
                se += e;
                sw = fmaf(e, s, sw);
            }
            scr[t] = sw / se;
        }
        if (t < 4 * WN) {                       // t2i: softmax over r per col
            int tile = t / WN, w = t % WN;
            const float* ir = snrow + tile * RN;
            float se = 0.f, sw = 0.f;
            for (int rr = 0; rr < RN; ++rr) {
                float s = sS[tile][rr][w];
                float e = __expf(leaky(s) * ir[rr]);
                se += e;
                sw = fmaf(e, s, sw);
            }
            scw[t] = sw / se;
        }
        __syncthreads();
    }

    if (t < 4) {
        float s1 = 0.f, s2 = 0.f;
        for (int w = 0; w < WN; ++w) s1 += scw[t * WN + w];
        for (int rr = 0; rr < RN; ++rr) s2 += scr[t * RN + rr];
        out[(size_t)(bi * 4 + 3) * CN + (bc * 4 + t)] = s1 / (float)WN + s2 / (float)RN;
    }
}

// ---------- fp32 fallback (used only if ws too small) ----------
__global__ __launch_bounds__(256, 4) void scan_fused(
    const float* __restrict__ img_emb, const float* __restrict__ cap_emb,
    float* __restrict__ out)
{
    __shared__ float s_img[48][68];
    __shared__ float s_cap[48][68];
    __shared__ float s_S[RN][WN + 1];
    __shared__ float s_nrow[RN];
    __shared__ float s_ncol[WN];
    __shared__ float s_cw[WN];
    __shared__ float s_cr[RN];

    const int t = threadIdx.x;
    const int c = blockIdx.x & (CN - 1);
    const int i = blockIdx.x >> 7;
    const float* imgB = img_emb + (size_t)i * RN * DN;
    const float* capB = cap_emb + (size_t)c * WN * DN;
    const int ty = t >> 4, tx = t & 15;

    float4 acc[3][3];
#pragma unroll
    for (int a = 0; a < 3; ++a)
#pragma unroll
        for (int b = 0; b < 3; ++b) acc[a][b] = make_float4(0.f, 0.f, 0.f, 0.f);

    for (int d0 = 0; d0 < DN; d0 += 64) {
#pragma unroll
        for (int p = 0; p < 3; ++p) {
            int idx = t + p * 256, row = idx >> 4, col = (idx & 15) << 2;
            float4 v = make_float4(0.f, 0.f, 0.f, 0.f);
            if (row < RN) v = *(const float4*)(imgB + row * DN + d0 + col);
            *(float4*)&s_img[row][col] = v;
        }
#pragma unroll
        for (int p = 0; p < 3; ++p) {
            int idx = t + p * 256, row = idx >> 4, col = (idx & 15) << 2;
            *(float4*)&s_cap[row][col] = *(const float4*)(capB + row * DN + d0 + col);
        }
        __syncthreads();
        for (int d = 0; d < 64; d += 4) {
            float4 a0 = *(float4*)&s_img[ty][d], a1 = *(float4*)&s_img[ty + 16][d], a2 = *(float4*)&s_img[ty + 32][d];
            float4 b0 = *(float4*)&s_cap[tx][d], b1 = *(float4*)&s_cap[tx + 16][d], b2 = *(float4*)&s_cap[tx + 32][d];
#define F4(ac, aa, bb) ac.x=fmaf(aa.x,bb.x,ac.x); ac.y=fmaf(aa.y,bb.y,ac.y); ac.z=fmaf(aa.z,bb.z,ac.z); ac.w=fmaf(aa.w,bb.w,ac.w)
            F4(acc[0][0],a0,b0); F4(acc[0][1],a0,b1); F4(acc[0][2],a0,b2);
            F4(acc[1][0],a1,b0); F4(acc[1][1],a1,b1); F4(acc[1][2],a1,b2);
            F4(acc[2][0],a2,b0); F4(acc[2][1],a2,b1); F4(acc[2][2],a2,b2);
#undef F4
        }
        __syncthreads();
    }
#pragma unroll
    for (int a = 0; a < 3; ++a) {
        int r = ty + 16 * a;
        if (r < RN)
#pragma unroll
            for (int b = 0; b < 3; ++b) {
                float4 v = acc[a][b];
                s_S[r][tx + 16 * b] = (v.x + v.y) + (v.z + v.w);
            }
    }
    __syncthreads();
    if (t < RN) {
        float ss = 0.f;
        for (int w = 0; w < WN; ++w) { float l = leaky(s_S[t][w]); ss = fmaf(l, l, ss); }
        s_nrow[t] = sqrtf(ss + EPSF) + EPSF;
    } else if (t >= 64 && t < 64 + WN) {
        int w = t - 64; float ss = 0.f;
        for (int r = 0; r < RN; ++r) { float l = leaky(s_S[r][w]); ss = fmaf(l, l, ss); }
        s_ncol[w] = sqrtf(ss + EPSF) + EPSF;
    }
    __syncthreads();
    if (t < RN) {
        float se = 0.f, sw = 0.f;
        for (int w = 0; w < WN; ++w) {
            float e = __expf(LAMF * leaky(s_S[t][w]) / s_ncol[w]);
            se += e; sw = fmaf(e, s_S[t][w], sw);
        }
        s_cr[t] = sw / se;
    } else if (t >= 64 && t < 64 + WN) {
        int w = t - 64;
        float se = 0.f, sw = 0.f;
        for (int r = 0; r < RN; ++r) {
            float e = __expf(LAMF * leaky(s_S[r][w]) / s_nrow[r]);
            se += e; sw = fmaf(e, s_S[r][w], sw);
        }
        s_cw[w] = sw / se;
    }
    __syncthreads();
    if (t == 0) {
        float t2i = 0.f, i2t = 0.f;
        for (int w = 0; w < WN; ++w) t2i += s_cw[w];
        for (int r = 0; r < RN; ++r) i2t += s_cr[r];
        out[(size_t)i * CN + c] = t2i / (float)WN + i2t / (float)RN;
    }
}

extern "C" void kernel_launch(void* const* d_in, const int* in_sizes, int n_in,
                              void* d_out, int out_size, void* d_ws, size_t ws_size,
                              hipStream_t stream) {
    const float* img = (const float*)d_in[0];
    const float* cap = (const float*)d_in[2];
    float* out = (float*)d_out;

    const size_t n_img = NIMG;                   // 4718592
    const size_t n_cap = (size_t)CN * WN * DN;   // 6291456
    const size_t need  = (n_img + n_cap) * 2;

    if (ws_size >= need) {
        unsigned short* imgh = (unsigned short*)d_ws;
        unsigned short* caph = imgh + n_img;
        int n4i = (int)(n_img / 4), n4c = (int)(n_cap / 4);
        hipLaunchKernelGGL(cvt_bf16, dim3((n4i + 255) / 256), dim3(256), 0, stream, img, imgh, n4i);
        hipLaunchKernelGGL(cvt_bf16, dim3((n4c + 255) / 256), dim3(256), 0, stream, cap, caph, n4c);
        hipLaunchKernelGGL(scan_mfma, dim3(IN / 4, CN / 4), dim3(256), 0, stream, imgh, out);
    } else {
        hipLaunchKernelGGL(scan_fused, dim3(IN * CN), dim3(256), 0, stream, img, cap, out);
    }
}

// Round 6
// 103.648 us; speedup vs baseline: 1.0181x; 1.0181x over previous
//
#include <hip/hip_runtime.h>
#include <hip/hip_bf16.h>

// SCAN similarity: out[i,c] = t2i[c,i] + i2t[c,i]
// g (global sim) cancels in the renormalization -> img_mean/cap_mean unused.
// bf16 MFMA, packed-A: block = 4 imgs (144 rows) x 4 caps (192 cols), 4 waves,
// wave = 9 row-tiles x 1 cap. global_load_lds dbuf with COUNTED-vmcnt split
// barriers (T4): no vmcnt(0) drain inside the K-loop. XOR-swizzled LDS.

#define EPSF 1e-8f
#define LAMF 9.0f

constexpr int IN = 128, CN = 128, RN = 36, WN = 48, DN = 1024;
constexpr size_t NIMG = (size_t)IN * RN * DN;   // 4718592 elems

constexpr int AROWS = 4 * RN;          // 144
constexpr int BROWS = 4 * WN;          // 192
constexpr int TROWS = AROWS + BROWS;   // 336 rows x 64 B = 21504 B per buffer
constexpr int BUFB  = TROWS * 64;      // 21504

using short8 = __attribute__((ext_vector_type(8))) short;
using f32x4  = __attribute__((ext_vector_type(4))) float;

__device__ __forceinline__ float leaky(float x) { return x > 0.f ? x : 0.1f * x; }

__device__ __forceinline__ unsigned short f2bf(float f) {
    unsigned int b = __float_as_uint(f);
    b += 0x7FFFu + ((b >> 16) & 1u);          // round-to-nearest-even
    return (unsigned short)(b >> 16);
}

__device__ __forceinline__ void gld_lds16(const unsigned short* g, void* l) {
    __builtin_amdgcn_global_load_lds(
        (const __attribute__((address_space(1))) unsigned int*)g,
        (__attribute__((address_space(3))) unsigned int*)l,
        16, 0, 0);
}

// ---------- preprocess: f32 -> bf16 ----------
__global__ void cvt_bf16(const float* __restrict__ in, unsigned short* __restrict__ out, int n4) {
    int idx = blockIdx.x * blockDim.x + threadIdx.x;
    if (idx >= n4) return;
    float4 v = ((const float4*)in)[idx];
    ushort4 o;
    o.x = f2bf(v.x); o.y = f2bf(v.y); o.z = f2bf(v.z); o.w = f2bf(v.w);
    ((ushort4*)out)[idx] = o;
}

// ---------- main MFMA kernel ----------
__global__ __launch_bounds__(256, 3) void scan_mfma(
    const unsigned short* __restrict__ wsb,   // imgh @0 [128][36][1024], caph @NIMG [128][48][1024]
    float* __restrict__ out)                  // [128][128], out[i*128+c]
{
    // staging dbuf: 2 x 21504 B. epilogue aliases (behind post-loop __syncthreads):
    //   sS[4][36][49] @0 (28224) | sncol @28224 (768) | snrow @28992 (576)
    //   scw @29568 (768) | scr @30336 (576) -> 30912
    __shared__ __align__(16) unsigned char smem[2 * BUFB];
    float (*sS)[RN][WN + 1] = (float (*)[RN][WN + 1])smem;
    float* sncol = (float*)(smem + 28224);   // [4][48] : LAMF / col_norm
    float* snrow = (float*)(smem + 28992);   // [4][36] : LAMF / row_norm
    float* scw   = (float*)(smem + 29568);   // [4][48]
    float* scr   = (float*)(smem + 30336);   // [4][36]

    const int t    = threadIdx.x;
    const int lane = t & 63;
    const int wid  = t >> 6;      // 0..3 ; wave's caption index
    const int lr   = lane & 15;
    const int lg   = lane >> 4;   // 0..3

    const int bi = blockIdx.x;    // image block (4 images)
    const int bc = blockIdx.y;    // caption block (4 captions)

    // ---- loop-invariant staging source offsets (elements) ----
    // granules g = j*256 + t (j=0..4) and tail g = 1280 + t (wave 0 only)
    unsigned int soff[6];
#pragma unroll
    for (int j = 0; j < 6; ++j) {
        int g = (j < 5) ? (j * 256 + t) : (1280 + t);
        int row = g >> 2, cg = g & 3;
        int sg = cg ^ ((row >> 1) & 3);
        unsigned int off;
        if (row < AROWS)
            off = (unsigned int)((bi * AROWS + row) << 10) + sg * 8;
        else
            off = (unsigned int)NIMG + (unsigned int)((bc * BROWS + (row - AROWS)) << 10) + sg * 8;
        soff[j] = off;
    }

    // fragment read swizzle (byte offset of this lane's 16B granule within its row)
    const int glo = ((lg ^ ((lr >> 1) & 3)) << 4);

    f32x4 acc[9][3];
#pragma unroll
    for (int rt = 0; rt < 9; ++rt)
#pragma unroll
        for (int ct = 0; ct < 3; ++ct) acc[rt][ct] = (f32x4)(0.f);

    // wave 0 issues 6 gld_lds per stage, waves 1-3 issue 5
    auto stage = [&](int bsel, int d0) {
        char* bufp = (char*)smem + bsel * BUFB;
#pragma unroll
        for (int j = 0; j < 5; ++j)
            gld_lds16(wsb + soff[j] + d0, bufp + j * 4096 + wid * 1024);
        if (t < 64)
            gld_lds16(wsb + soff[5] + d0, bufp + 20480);
    };

    stage(0, 0);

    for (int ch = 0; ch < 32; ++ch) {
        // barrier A: all waves finished reading buf[(ch+1)&1] (iter ch-1's compute)
        __builtin_amdgcn_s_barrier();
        if (ch < 31) {
            stage((ch & 1) ^ 1, (ch + 1) * 32);
            // counted wait: my stage(ch) loads complete; stage(ch+1)'s stay in flight
            if (wid == 0) asm volatile("s_waitcnt vmcnt(6)" ::: "memory");
            else          asm volatile("s_waitcnt vmcnt(5)" ::: "memory");
        } else {
            asm volatile("s_waitcnt vmcnt(0)" ::: "memory");
        }
        // barrier B: all waves' stage(ch) writes are in LDS
        __builtin_amdgcn_s_barrier();
        __builtin_amdgcn_sched_barrier(0);

        const char* bufp = (const char*)smem + (ch & 1) * BUFB;
        const char* ap = bufp + lr * 64 + glo;                                  // rt stride 1024
        const char* bp = bufp + (AROWS + wid * WN + lr) * 64 + glo;             // ct stride 1024
        short8 b0 = *(const short8*)(bp);
        short8 b1 = *(const short8*)(bp + 1024);
        short8 b2 = *(const short8*)(bp + 2048);

        __builtin_amdgcn_s_setprio(1);
#pragma unroll
        for (int rt = 0; rt < 9; ++rt) {
            short8 a = *(const short8*)(ap + rt * 1024);
            acc[rt][0] = __builtin_amdgcn_mfma_f32_16x16x32_bf16(a, b0, acc[rt][0], 0, 0, 0);
            acc[rt][1] = __builtin_amdgcn_mfma_f32_16x16x32_bf16(a, b1, acc[rt][1], 0, 0, 0);
            acc[rt][2] = __builtin_amdgcn_mfma_f32_16x16x32_bf16(a, b2, acc[rt][2], 0, 0, 0);
        }
        __builtin_amdgcn_s_setprio(0);
    }
    __syncthreads();   // full drain before epilogue aliases the staging buffers

    // ---- epilogue: 4 rounds, round r = image bi*4+r, 4 tiles (one per cap/wave) ----
    // C/D layout: col = lane&15, row = (lane>>4)*4 + reg   [m89-verified]
#pragma unroll
    for (int r = 0; r < 4; ++r) {
        if (r > 0 && t < 4) {
            // finalize round r-1 (reads scr/scw; disjoint from sS writes below;
            // softmax for round r writes scr/scw only after two more barriers)
            float s1 = 0.f, s2 = 0.f;
            for (int w = 0; w < WN; ++w) s1 += scw[t * WN + w];
            for (int rr = 0; rr < RN; ++rr) s2 += scr[t * RN + rr];
            out[(size_t)(bi * 4 + (r - 1)) * CN + (bc * 4 + t)] = s1 / (float)WN + s2 / (float)RN;
        }
        // dump: each wave writes rows of image r from its acc (tile slot = wid)
#pragma unroll
        for (int rt = 0; rt < 9; ++rt)
#pragma unroll
            for (int reg = 0; reg < 4; ++reg) {
                int lrow = rt * 16 + lg * 4 + reg;     // 0..143
                int ii = lrow / 36;
                if (ii == r) {
                    int rin = lrow - ii * 36;
#pragma unroll
                    for (int ct = 0; ct < 3; ++ct)
                        sS[wid][rin][ct * 16 + lr] = acc[rt][ct][reg];
                }
            }
        __syncthreads();

        // inverse l2 norms (scaled by LAMF)
        if (t < 4 * WN) {                       // col norms over r
            int tile = t / WN, w = t % WN;
            float ss = 0.f;
            for (int rr = 0; rr < RN; ++rr) { float l = leaky(sS[tile][rr][w]); ss = fmaf(l, l, ss); }
            sncol[t] = LAMF / (sqrtf(ss + EPSF) + EPSF);
        }
        if (t < 4 * RN) {                       // row norms over w
            int tile = t / RN, rr = t % RN;
            float ss = 0.f;
            for (int w = 0; w < WN; ++w) { float l = leaky(sS[tile][rr][w]); ss = fmaf(l, l, ss); }
            snrow[t] = LAMF / (sqrtf(ss + EPSF) + EPSF);
        }
        __syncthreads();

        // single-pass softmaxes (arg bounded by LAMF => no max pass)
        if (t < 4 * RN) {                       // i2t: softmax over w per row
            int tile = t / RN, rr = t % RN;
            const float* Sr = sS[tile][rr];
            const float* ic = sncol + tile * WN;
            float se = 0.f, sw = 0.f;
            for (int w = 0; w < WN; ++w) {
                float s = Sr[w];
                float e = __expf(leaky(s) * ic[w]);
                se += e;
                sw = fmaf(e, s, sw);
            }
            scr[t] = sw / se;
        }
        if (t < 4 * WN) {                       // t2i: softmax over r per col
            int tile = t / WN, w = t % WN;
            const float* ir = snrow + tile * RN;
            float se = 0.f, sw = 0.f;
            for (int rr = 0; rr < RN; ++rr) {
                float s = sS[tile][rr][w];
                float e = __expf(leaky(s) * ir[rr]);
                se += e;
                sw = fmaf(e, s, sw);
            }
            scw[t] = sw / se;
        }
        __syncthreads();
    }

    if (t < 4) {
        float s1 = 0.f, s2 = 0.f;
        for (int w = 0; w < WN; ++w) s1 += scw[t * WN + w];
        for (int rr = 0; rr < RN; ++rr) s2 += scr[t * RN + rr];
        out[(size_t)(bi * 4 + 3) * CN + (bc * 4 + t)] = s1 / (float)WN + s2 / (float)RN;
    }
}

// ---------- fp32 fallback (used only if ws too small) ----------
__global__ __launch_bounds__(256, 4) void scan_fused(
    const float* __restrict__ img_emb, const float* __restrict__ cap_emb,
    float* __restrict__ out)
{
    __shared__ float s_img[48][68];
    __shared__ float s_cap[48][68];
    __shared__ float s_S[RN][WN + 1];
    __shared__ float s_nrow[RN];
    __shared__ float s_ncol[WN];
    __shared__ float s_cw[WN];
    __shared__ float s_cr[RN];

    const int t = threadIdx.x;
    const int c = blockIdx.x & (CN - 1);
    const int i = blockIdx.x >> 7;
    const float* imgB = img_emb + (size_t)i * RN * DN;
    const float* capB = cap_emb + (size_t)c * WN * DN;
    const int ty = t >> 4, tx = t & 15;

    float4 acc[3][3];
#pragma unroll
    for (int a = 0; a < 3; ++a)
#pragma unroll
        for (int b = 0; b < 3; ++b) acc[a][b] = make_float4(0.f, 0.f, 0.f, 0.f);

    for (int d0 = 0; d0 < DN; d0 += 64) {
#pragma unroll
        for (int p = 0; p < 3; ++p) {
            int idx = t + p * 256, row = idx >> 4, col = (idx & 15) << 2;
            float4 v = make_float4(0.f, 0.f, 0.f, 0.f);
            if (row < RN) v = *(const float4*)(imgB + row * DN + d0 + col);
            *(float4*)&s_img[row][col] = v;
        }
#pragma unroll
        for (int p = 0; p < 3; ++p) {
            int idx = t + p * 256, row = idx >> 4, col = (idx & 15) << 2;
            *(float4*)&s_cap[row][col] = *(const float4*)(capB + row * DN + d0 + col);
        }
        __syncthreads();
        for (int d = 0; d < 64; d += 4) {
            float4 a0 = *(float4*)&s_img[ty][d], a1 = *(float4*)&s_img[ty + 16][d], a2 = *(float4*)&s_img[ty + 32][d];
            float4 b0 = *(float4*)&s_cap[tx][d], b1 = *(float4*)&s_cap[tx + 16][d], b2 = *(float4*)&s_cap[tx + 32][d];
#define F4(ac, aa, bb) ac.x=fmaf(aa.x,bb.x,ac.x); ac.y=fmaf(aa.y,bb.y,ac.y); ac.z=fmaf(aa.z,bb.z,ac.z); ac.w=fmaf(aa.w,bb.w,ac.w)
            F4(acc[0][0],a0,b0); F4(acc[0][1],a0,b1); F4(acc[0][2],a0,b2);
            F4(acc[1][0],a1,b0); F4(acc[1][1],a1,b1); F4(acc[1][2],a1,b2);
            F4(acc[2][0],a2,b0); F4(acc[2][1],a2,b1); F4(acc[2][2],a2,b2);
#undef F4
        }
        __syncthreads();
    }
#pragma unroll
    for (int a = 0; a < 3; ++a) {
        int r = ty + 16 * a;
        if (r < RN)
#pragma unroll
            for (int b = 0; b < 3; ++b) {
                float4 v = acc[a][b];
                s_S[r][tx + 16 * b] = (v.x + v.y) + (v.z + v.w);
            }
    }
    __syncthreads();
    if (t < RN) {
        float ss = 0.f;
        for (int w = 0; w < WN; ++w) { float l = leaky(s_S[t][w]); ss = fmaf(l, l, ss); }
        s_nrow[t] = sqrtf(ss + EPSF) + EPSF;
    } else if (t >= 64 && t < 64 + WN) {
        int w = t - 64; float ss = 0.f;
        for (int r = 0; r < RN; ++r) { float l = leaky(s_S[r][w]); ss = fmaf(l, l, ss); }
        s_ncol[w] = sqrtf(ss + EPSF) + EPSF;
    }
    __syncthreads();
    if (t < RN) {
        float se = 0.f, sw = 0.f;
        for (int w = 0; w < WN; ++w) {
            float e = __expf(LAMF * leaky(s_S[t][w]) / s_ncol[w]);
            se += e; sw = fmaf(e, s_S[t][w], sw);
        }
        s_cr[t] = sw / se;
    } else if (t >= 64 && t < 64 + WN) {
        int w = t - 64;
        float se = 0.f, sw = 0.f;
        for (int r = 0; r < RN; ++r) {
            float e = __expf(LAMF * leaky(s_S[r][w]) / s_nrow[r]);
            se += e; sw = fmaf(e, s_S[r][w], sw);
        }
        s_cw[w] = sw / se;
    }
    __syncthreads();
    if (t == 0) {
        float t2i = 0.f, i2t = 0.f;
        for (int w = 0; w < WN; ++w) t2i += s_cw[w];
        for (int r = 0; r < RN; ++r) i2t += s_cr[r];
        out[(size_t)i * CN + c] = t2i / (float)WN + i2t / (float)RN;
    }
}

extern "C" void kernel_launch(void* const* d_in, const int* in_sizes, int n_in,
                              void* d_out, int out_size, void* d_ws, size_t ws_size,
                              hipStream_t stream) {
    const float* img = (const float*)d_in[0];
    const float* cap = (const float*)d_in[2];
    float* out = (float*)d_out;

    const size_t n_img = NIMG;                   // 4718592
    const size_t n_cap = (size_t)CN * WN * DN;   // 6291456
    const size_t need  = (n_img + n_cap) * 2;

    if (ws_size >= need) {
        unsigned short* imgh = (unsigned short*)d_ws;
        unsigned short* caph = imgh + n_img;
        int n4i = (int)(n_img / 4), n4c = (int)(n_cap / 4);
        hipLaunchKernelGGL(cvt_bf16, dim3((n4i + 255) / 256), dim3(256), 0, stream, img, imgh, n4i);
        hipLaunchKernelGGL(cvt_bf16, dim3((n4c + 255) / 256), dim3(256), 0, stream, cap, caph, n4c);
        hipLaunchKernelGGL(scan_mfma, dim3(IN / 4, CN / 4), dim3(256), 0, stream, imgh, out);
    } else {
        hipLaunchKernelGGL(scan_fused, dim3(IN * CN), dim3(256), 0, stream, img, cap, out);
    }
}

// Round 7
// 97.134 us; speedup vs baseline: 1.0863x; 1.0671x over previous
//
#include <hip/hip_runtime.h>
#include <hip/hip_bf16.h>

// SCAN similarity: out[i,c] = t2i[c,i] + i2t[c,i]
// g (global sim) cancels in the renormalization -> img_mean/cap_mean unused.
// bf16 MFMA, packed-A 4i x 4c tile, 12 waves of 3x3 tiles (small acc => 6
// waves/SIMD under the UNIFIED VGPR+AGPR file), gld_lds dbuf, counted vmcnt,
// XOR-swizzled LDS, 2-round x 8-tile softmax epilogue.

#define EPSF 1e-8f
#define LAMF 9.0f

constexpr int IN = 128, CN = 128, RN = 36, WN = 48, DN = 1024;
constexpr size_t NIMG = (size_t)IN * RN * DN;   // 4718592 elems

constexpr int AROWS = 4 * RN;          // 144
constexpr int BROWS = 4 * WN;          // 192
constexpr int TROWS = AROWS + BROWS;   // 336 rows x 64 B = 21504 B per buffer
constexpr int BUFB  = TROWS * 64;      // 21504

using short8 = __attribute__((ext_vector_type(8))) short;
using f32x4  = __attribute__((ext_vector_type(4))) float;

__device__ __forceinline__ float leaky(float x) { return x > 0.f ? x : 0.1f * x; }

__device__ __forceinline__ unsigned short f2bf(float f) {
    unsigned int b = __float_as_uint(f);
    b += 0x7FFFu + ((b >> 16) & 1u);          // round-to-nearest-even
    return (unsigned short)(b >> 16);
}

__device__ __forceinline__ void gld_lds16(const unsigned short* g, void* l) {
    __builtin_amdgcn_global_load_lds(
        (const __attribute__((address_space(1))) unsigned int*)g,
        (__attribute__((address_space(3))) unsigned int*)l,
        16, 0, 0);
}

// ---------- preprocess: f32 -> bf16 ----------
__global__ void cvt_bf16(const float* __restrict__ in, unsigned short* __restrict__ out, int n4) {
    int idx = blockIdx.x * blockDim.x + threadIdx.x;
    if (idx >= n4) return;
    float4 v = ((const float4*)in)[idx];
    ushort4 o;
    o.x = f2bf(v.x); o.y = f2bf(v.y); o.z = f2bf(v.z); o.w = f2bf(v.w);
    ((ushort4*)out)[idx] = o;
}

// ---------- main MFMA kernel ----------
// block = 4 imgs x 4 caps, 768 threads = 12 waves = 3 row-thirds x 4 caps.
// Wave (wrt,wct): rows [wrt*48, +48) of packed-A (144 rows), cap wct (48 cols).
// Per K32 chunk per wave: 3 a-reads + 3 b-reads + 9 MFMA; acc[3][3] = 36 regs.
__global__ __launch_bounds__(768, 6) void scan_mfma(
    const unsigned short* __restrict__ wsb,   // imgh @0 [128][36][1024], caph @NIMG [128][48][1024]
    float* __restrict__ out)                  // [128][128], out[i*128+c]
{
    // staging dbuf: 2 x 21504 B in [0, 43008). epilogue (after K-loop barrier):
    //   sS[8][36][49] @0 (56448) | sncol @56448 (1536) | snrow @57984 (1152)
    //   scw @59136 (1536) | scr @60672 (1152) -> 61824
    __shared__ __align__(16) unsigned char smem[61824];
    float (*sS)[RN][WN + 1] = (float (*)[RN][WN + 1])smem;
    float* sncol = (float*)(smem + 56448);   // [8][48] : LAMF / col_norm
    float* snrow = (float*)(smem + 57984);   // [8][36] : LAMF / row_norm
    float* scw   = (float*)(smem + 59136);   // [8][48]
    float* scr   = (float*)(smem + 60672);   // [8][36]

    const int t    = threadIdx.x;
    const int lane = t & 63;
    const int wid  = t >> 6;      // 0..11
    const int lr   = lane & 15;
    const int lg   = lane >> 4;   // 0..3
    const int wrt  = wid % 3;     // row-third: rows wrt*48 .. +48
    const int wct  = wid / 3;     // caption 0..3: cols wct*48 .. +48

    const int bi = blockIdx.x;    // image block (4 images)
    const int bc = blockIdx.y;    // caption block (4 captions)

    // ---- loop-invariant staging source offsets (elements) ----
    // granules g = t (all) and g = 768 + t (t < 576); row = g>>2, swizzled granule
    unsigned int soff[2];
#pragma unroll
    for (int j = 0; j < 2; ++j) {
        int g = j * 768 + t;
        int row = g >> 2, cg = g & 3;
        int sg = cg ^ ((row >> 1) & 3);
        unsigned int off;
        if (row < AROWS)
            off = (unsigned int)((bi * AROWS + row) << 10) + sg * 8;
        else
            off = (unsigned int)NIMG + (unsigned int)((bc * BROWS + (row - AROWS)) << 10) + sg * 8;
        soff[j] = off;
    }

    // fragment read swizzle (byte offset of this lane's 16B granule within its row)
    const int glo = ((lg ^ ((lr >> 1) & 3)) << 4);
    const int aoff = (wrt * 48 + lr) * 64 + glo;             // rt stride 1024 B
    const int boff = (AROWS + wct * 48 + lr) * 64 + glo;     // ct stride 1024 B

    f32x4 acc[3][3];
#pragma unroll
    for (int rt = 0; rt < 3; ++rt)
#pragma unroll
        for (int ct = 0; ct < 3; ++ct) acc[rt][ct] = (f32x4)(0.f);

    // waves 0..8 issue 2 gld_lds per stage, waves 9..11 issue 1
    auto stage = [&](int bsel, int d0) {
        char* bufp = (char*)smem + bsel * BUFB;
        gld_lds16(wsb + soff[0] + d0, bufp + wid * 1024);
        if (t < 576)
            gld_lds16(wsb + soff[1] + d0, bufp + 12288 + wid * 1024);
    };

    stage(0, 0);

    for (int ch = 0; ch < 32; ++ch) {
        // barrier A: all waves finished reading buf[(ch+1)&1] (iter ch-1's compute)
        __builtin_amdgcn_s_barrier();
        if (ch < 31) {
            stage((ch & 1) ^ 1, (ch + 1) * 32);
            // counted wait: my stage(ch) loads complete; stage(ch+1)'s stay in flight
            if (wid < 9) asm volatile("s_waitcnt vmcnt(2)" ::: "memory");
            else         asm volatile("s_waitcnt vmcnt(1)" ::: "memory");
        } else {
            asm volatile("s_waitcnt vmcnt(0)" ::: "memory");
        }
        // barrier B: all waves' stage(ch) writes are in LDS
        __builtin_amdgcn_s_barrier();
        __builtin_amdgcn_sched_barrier(0);

        const char* bufp = (const char*)smem + (ch & 1) * BUFB;
        const char* ap = bufp + aoff;
        const char* bp = bufp + boff;
        short8 a0 = *(const short8*)(ap);
        short8 a1 = *(const short8*)(ap + 1024);
        short8 a2 = *(const short8*)(ap + 2048);
        short8 b0 = *(const short8*)(bp);
        short8 b1 = *(const short8*)(bp + 1024);
        short8 b2 = *(const short8*)(bp + 2048);

        __builtin_amdgcn_s_setprio(1);
        acc[0][0] = __builtin_amdgcn_mfma_f32_16x16x32_bf16(a0, b0, acc[0][0], 0, 0, 0);
        acc[0][1] = __builtin_amdgcn_mfma_f32_16x16x32_bf16(a0, b1, acc[0][1], 0, 0, 0);
        acc[0][2] = __builtin_amdgcn_mfma_f32_16x16x32_bf16(a0, b2, acc[0][2], 0, 0, 0);
        acc[1][0] = __builtin_amdgcn_mfma_f32_16x16x32_bf16(a1, b0, acc[1][0], 0, 0, 0);
        acc[1][1] = __builtin_amdgcn_mfma_f32_16x16x32_bf16(a1, b1, acc[1][1], 0, 0, 0);
        acc[1][2] = __builtin_amdgcn_mfma_f32_16x16x32_bf16(a1, b2, acc[1][2], 0, 0, 0);
        acc[2][0] = __builtin_amdgcn_mfma_f32_16x16x32_bf16(a2, b0, acc[2][0], 0, 0, 0);
        acc[2][1] = __builtin_amdgcn_mfma_f32_16x16x32_bf16(a2, b1, acc[2][1], 0, 0, 0);
        acc[2][2] = __builtin_amdgcn_mfma_f32_16x16x32_bf16(a2, b2, acc[2][2], 0, 0, 0);
        __builtin_amdgcn_s_setprio(0);
    }
    __syncthreads();   // full drain before epilogue aliases the staging buffers

    // ---- epilogue: 2 rounds x 8 tiles (2 imgs x 4 caps per round) ----
    // C/D layout: col = lane&15, row = (lane>>4)*4 + reg   [m89-verified]
#pragma unroll
    for (int r = 0; r < 2; ++r) {
        if (r == 1 && t < 8) {
            // finalize round 0 (reads scr/scw; disjoint from sS writes below)
            float s1 = 0.f, s2 = 0.f;
            for (int w = 0; w < WN; ++w) s1 += scw[t * WN + w];
            for (int rr = 0; rr < RN; ++rr) s2 += scr[t * RN + rr];
            out[(size_t)(bi * 4 + (t >> 2)) * CN + (bc * 4 + (t & 3))] =
                s1 / (float)WN + s2 / (float)RN;
        }
        // dump: wave (wrt,wct) writes its rows of images {2r, 2r+1}
#pragma unroll
        for (int rt = 0; rt < 3; ++rt)
#pragma unroll
            for (int reg = 0; reg < 4; ++reg) {
                int lrow = wrt * 48 + rt * 16 + lg * 4 + reg;   // 0..143
                int ii = lrow / 36;
                if ((ii >> 1) == r) {
                    int tile = (ii & 1) * 4 + wct;
                    int rin = lrow - ii * 36;
#pragma unroll
                    for (int ct = 0; ct < 3; ++ct)
                        sS[tile][rin][ct * 16 + lr] = acc[rt][ct][reg];
                }
            }
        __syncthreads();

        // inverse l2 norms (scaled by LAMF)
        if (t < 8 * WN) {                       // col norms over r
            int tile = t / WN, w = t % WN;
            float ss = 0.f;
            for (int rr = 0; rr < RN; ++rr) { float l = leaky(sS[tile][rr][w]); ss = fmaf(l, l, ss); }
            sncol[t] = LAMF / (sqrtf(ss + EPSF) + EPSF);
        }
        if (t < 8 * RN) {                       // row norms over w
            int tile = t / RN, rr = t % RN;
            float ss = 0.f;
            for (int w = 0; w < WN; ++w) { float l = leaky(sS[tile][rr][w]); ss = fmaf(l, l, ss); }
            snrow[t] = LAMF / (sqrtf(ss + EPSF) + EPSF);
        }
        __syncthreads();

        // single-pass softmaxes (arg bounded by LAMF => no max pass)
        if (t < 8 * RN) {                       // i2t: softmax over w per row
            int tile = t / RN, rr = t % RN;
            const float* Sr = sS[tile][rr];
            const float* ic = sncol + tile * WN;
            float se = 0.f, sw = 0.f;
            for (int w = 0; w < WN; ++w) {
                float s = Sr[w];
                float e = __expf(leaky(s) * ic[w]);
                se += e;
                sw = fmaf(e, s, sw);
            }
            scr[t] = sw / se;
        }
        if (t < 8 * WN) {                       // t2i: softmax over r per col
            int tile = t / WN, w = t % WN;
            const float* ir = snrow + tile * RN;
            float se = 0.f, sw = 0.f;
            for (int rr = 0; rr < RN; ++rr) {
                float s = sS[tile][rr][w];
                float e = __expf(leaky(s) * ir[rr]);
                se += e;
                sw = fmaf(e, s, sw);
            }
            scw[t] = sw / se;
        }
        __syncthreads();
    }

    if (t < 8) {
        float s1 = 0.f, s2 = 0.f;
        for (int w = 0; w < WN; ++w) s1 += scw[t * WN + w];
        for (int rr = 0; rr < RN; ++rr) s2 += scr[t * RN + rr];
        out[(size_t)(bi * 4 + 2 + (t >> 2)) * CN + (bc * 4 + (t & 3))] =
            s1 / (float)WN + s2 / (float)RN;
    }
}

// ---------- fp32 fallback (used only if ws too small) ----------
__global__ __launch_bounds__(256, 4) void scan_fused(
    const float* __restrict__ img_emb, const float* __restrict__ cap_emb,
    float* __restrict__ out)
{
    __shared__ float s_img[48][68];
    __shared__ float s_cap[48][68];
    __shared__ float s_S[RN][WN + 1];
    __shared__ float s_nrow[RN];
    __shared__ float s_ncol[WN];
    __shared__ float s_cw[WN];
    __shared__ float s_cr[RN];

    const int t = threadIdx.x;
    const int c = blockIdx.x & (CN - 1);
    const int i = blockIdx.x >> 7;
    const float* imgB = img_emb + (size_t)i * RN * DN;
    const float* capB = cap_emb + (size_t)c * WN * DN;
    const int ty = t >> 4, tx = t & 15;

    float4 acc[3][3];
#pragma unroll
    for (int a = 0; a < 3; ++a)
#pragma unroll
        for (int b = 0; b < 3; ++b) acc[a][b] = make_float4(0.f, 0.f, 0.f, 0.f);

    for (int d0 = 0; d0 < DN; d0 += 64) {
#pragma unroll
        for (int p = 0; p < 3; ++p) {
            int idx = t + p * 256, row = idx >> 4, col = (idx & 15) << 2;
            float4 v = make_float4(0.f, 0.f, 0.f, 0.f);
            if (row < RN) v = *(const float4*)(imgB + row * DN + d0 + col);
            *(float4*)&s_img[row][col] = v;
        }
#pragma unroll
        for (int p = 0; p < 3; ++p) {
            int idx = t + p * 256, row = idx >> 4, col = (idx & 15) << 2;
            *(float4*)&s_cap[row][col] = *(const float4*)(capB + row * DN + d0 + col);
        }
        __syncthreads();
        for (int d = 0; d < 64; d += 4) {
            float4 a0 = *(float4*)&s_img[ty][d], a1 = *(float4*)&s_img[ty + 16][d], a2 = *(float4*)&s_img[ty + 32][d];
            float4 b0 = *(float4*)&s_cap[tx][d], b1 = *(float4*)&s_cap[tx + 16][d], b2 = *(float4*)&s_cap[tx + 32][d];
#define F4(ac, aa, bb) ac.x=fmaf(aa.x,bb.x,ac.x); ac.y=fmaf(aa.y,bb.y,ac.y); ac.z=fmaf(aa.z,bb.z,ac.z); ac.w=fmaf(aa.w,bb.w,ac.w)
            F4(acc[0][0],a0,b0); F4(acc[0][1],a0,b1); F4(acc[0][2],a0,b2);
            F4(acc[1][0],a1,b0); F4(acc[1][1],a1,b1); F4(acc[1][2],a1,b2);
            F4(acc[2][0],a2,b0); F4(acc[2][1],a2,b1); F4(acc[2][2],a2,b2);
#undef F4
        }
        __syncthreads();
    }
#pragma unroll
    for (int a = 0; a < 3; ++a) {
        int r = ty + 16 * a;
        if (r < RN)
#pragma unroll
            for (int b = 0; b < 3; ++b) {
                float4 v = acc[a][b];
                s_S[r][tx + 16 * b] = (v.x + v.y) + (v.z + v.w);
            }
    }
    __syncthreads();
    if (t < RN) {
        float ss = 0.f;
        for (int w = 0; w < WN; ++w) { float l = leaky(s_S[t][w]); ss = fmaf(l, l, ss); }
        s_nrow[t] = sqrtf(ss + EPSF) + EPSF;
    } else if (t >= 64 && t < 64 + WN) {
        int w = t - 64; float ss = 0.f;
        for (int r = 0; r < RN; ++r) { float l = leaky(s_S[r][w]); ss = fmaf(l, l, ss); }
        s_ncol[w] = sqrtf(ss + EPSF) + EPSF;
    }
    __syncthreads();
    if (t < RN) {
        float se = 0.f, sw = 0.f;
        for (int w = 0; w < WN; ++w) {
            float e = __expf(LAMF * leaky(s_S[t][w]) / s_ncol[w]);
            se += e; sw = fmaf(e, s_S[t][w], sw);
        }
        s_cr[t] = sw / se;
    } else if (t >= 64 && t < 64 + WN) {
        int w = t - 64;
        float se = 0.f, sw = 0.f;
        for (int r = 0; r < RN; ++r) {
            float e = __expf(LAMF * leaky(s_S[r][w]) / s_nrow[r]);
            se += e; sw = fmaf(e, s_S[r][w], sw);
        }
        s_cw[w] = sw / se;
    }
    __syncthreads();
    if (t == 0) {
        float t2i = 0.f, i2t = 0.f;
        for (int w = 0; w < WN; ++w) t2i += s_cw[w];
        for (int r = 0; r < RN; ++r) i2t += s_cr[r];
        out[(size_t)i * CN + c] = t2i / (float)WN + i2t / (float)RN;
    }
}

extern "C" void kernel_launch(void* const* d_in, const int* in_sizes, int n_in,
                              void* d_out, int out_size, void* d_ws, size_t ws_size,
                              hipStream_t stream) {
    const float* img = (const float*)d_in[0];
    const float* cap = (const float*)d_in[2];
    float* out = (float*)d_out;

    const size_t n_img = NIMG;                   // 4718592
    const size_t n_cap = (size_t)CN * WN * DN;   // 6291456
    const size_t need  = (n_img + n_cap) * 2;

    if (ws_size >= need) {
        unsigned short* imgh = (unsigned short*)d_ws;
        unsigned short* caph = imgh + n_img;
        int n4i = (int)(n_img / 4), n4c = (int)(n_cap / 4);
        hipLaunchKernelGGL(cvt_bf16, dim3((n4i + 255) / 256), dim3(256), 0, stream, img, imgh, n4i);
        hipLaunchKernelGGL(cvt_bf16, dim3((n4c + 255) / 256), dim3(256), 0, stream, cap, caph, n4c);
        hipLaunchKernelGGL(scan_mfma, dim3(IN / 4, CN / 4), dim3(768), 0, stream, imgh, out);
    } else {
        hipLaunchKernelGGL(scan_fused, dim3(IN * CN), dim3(256), 0, stream, img, cap, out);
    }
}